// Round 1
// baseline (474.118 us; speedup 1.0000x reference)
//
#include <hip/hip_runtime.h>

#define DIMX   4096
#define KROT   8
#define GROUPC 128
#define NGG    32
#define NROWS  16384
#define RPT    128                        // rows per task (one block-task)
#define NTASKS (NGG * (NROWS / RPT))      // 32 * 128 = 4096

// Workspace layout:
//   cs : float[2 * KROT * 2048]   interleaved (cos, sin) per rotation   = 128 KiB
//   ao : int [2 * KROT * 64]      pre-swizzled LDS byte offsets (Aa,Ab) =   4 KiB
// Re-poisoned every timed launch -> setup kernel runs every kernel_launch.

__global__ void rot_setup(const float* __restrict__ theta,
                          const int* __restrict__ pairs,
                          float* __restrict__ cs, int* __restrict__ ao) {
    int i = blockIdx.x * 256 + threadIdx.x;
    if (i < KROT * (DIMX / 2)) {
        float t = theta[i];
        cs[2 * i]     = cosf(t);
        cs[2 * i + 1] = sinf(t);
    }
    if (i < KROT * 64) {
        int k = i >> 6, p = i & 63;
        int ie = pairs[k * DIMX + 2 * p];       // local perm values, 0..127
        int io = pairs[k * DIMX + 2 * p + 1];
        // byte offset of channel ch in lds[ch][row] (RPT=128 f32 rows = 512 B)
        // plus the row-XOR swizzle constant for that channel, pre-scaled:
        //   e(ch) = ((ch>>1)&31)<<1  (row units, even)  -> bytes = e<<2
        ao[2 * i]     = (ie << 9) | (((ie >> 1) & 31) << 3);
        ao[2 * i + 1] = (io << 9) | (((io >> 1) & 31) << 3);
    }
}

__global__ __launch_bounds__(256) void rot_main(
    const float* __restrict__ x, const float* __restrict__ scales,
    const float* __restrict__ cs, const int* __restrict__ ao,
    float* __restrict__ out) {
    __shared__ float lds[RPT * GROUPC];   // 64 KiB: lds[channel][row^e]
    const int tid  = threadIdx.x;
    const int lane = tid & 63;
    const int wave = tid >> 6;
    const int c    = lane * 2;                  // channel pair staged by this thread
    const int eb   = (lane & 31) << 1;          // row-slot xor for channels (c, c+1)
    // force wave-uniform rotation base into an SGPR so cs/ao loads become s_load
    const int wbase = __builtin_amdgcn_readfirstlane(wave * 16);
    char* lp = (char*)lds;

    for (int task = blockIdx.x; task < NTASKS; task += gridDim.x) {
        const int rowblock = task >> 5;
        const int g        = task & 31;
        const float* xb = x   + (size_t)rowblock * RPT * DIMX + g * GROUPC;
        float*       ob = out + (size_t)rowblock * RPT * DIMX + g * GROUPC;

        __syncthreads();   // previous task's readers are done with the buffer

        // ---- stage: transpose x[row][ch] -> lds[ch][row ^ e(ch)] ----
        // global float2 coalesced (512 B / wave); LDS writes are 2-way (free)
        #pragma unroll 8
        for (int it = 0; it < RPT / 4; ++it) {
            int t = it * 4 + wave;
            float2 v = *(const float2*)(xb + (size_t)t * DIMX + c);
            int slot = t ^ eb;
            lds[c * RPT + slot]       = v.x;
            lds[(c + 1) * RPT + slot] = v.y;
        }
        __syncthreads();

        // ---- 8 rounds x 64 rotations; wave w owns rotations [16w,16w+16) ----
        // lane l carries rows (2l, 2l+1) via ds_*_b64; indices & cos/sin are
        // wave-uniform (s_load). All DS ops conflict-free by construction.
        for (int k = 0; k < KROT; ++k) {
            const float* csb = cs + ((k * 2048 + g * 64) << 1);
            const int*   aob = ao + (k << 7);
            #pragma unroll
            for (int i = 0; i < 16; ++i) {
                int p = wbase + i;
                int2   A = *(const int2*)(aob + 2 * p);
                float2 w = *(const float2*)(csb + 2 * p);
                float2 a = *(float2*)(lp + (A.x ^ (lane << 3)));
                float2 b = *(float2*)(lp + (A.y ^ (lane << 3)));
                float2 na, nb;
                na.x = a.x * w.x - b.x * w.y;
                na.y = a.y * w.x - b.y * w.y;
                nb.x = a.x * w.y + b.x * w.x;
                nb.y = a.y * w.y + b.y * w.x;
                *(float2*)(lp + (A.x ^ (lane << 3))) = na;
                *(float2*)(lp + (A.y ^ (lane << 3))) = nb;
            }
            __syncthreads();
        }

        // ---- output: per-channel scale, store coalesced ----
        float2 sc = *(const float2*)(scales + g * GROUPC + c);
        #pragma unroll 8
        for (int it = 0; it < RPT / 4; ++it) {
            int t = it * 4 + wave;
            int slot = t ^ eb;
            float2 v;
            v.x = lds[c * RPT + slot]       * sc.x;
            v.y = lds[(c + 1) * RPT + slot] * sc.y;
            *(float2*)(ob + (size_t)t * DIMX + c) = v;
        }
    }
}

extern "C" void kernel_launch(void* const* d_in, const int* in_sizes, int n_in,
                              void* d_out, int out_size, void* d_ws, size_t ws_size,
                              hipStream_t stream) {
    const float* x      = (const float*)d_in[0];
    const int*   pairs  = (const int*)d_in[1];
    const float* theta  = (const float*)d_in[2];
    const float* scales = (const float*)d_in[3];
    float* outp = (float*)d_out;

    float* cs = (float*)d_ws;
    int*   ao = (int*)((char*)d_ws + (size_t)2 * KROT * 2048 * sizeof(float));

    rot_setup<<<64, 256, 0, stream>>>(theta, pairs, cs, ao);
    rot_main<<<512, 256, 0, stream>>>(x, scales, cs, ao, outp);
}